// Round 1
// baseline (68.476 us; speedup 1.0000x reference)
//
#include <hip/hip_runtime.h>
#include <stdint.h>

// SpikeFP32Sqrt: reference emulates fp32 sqrt via soft logic gates on 0/1 floats.
// We pack each 32-float row into a uint32, run the identical digit-recurrence
// sqrt in integer arithmetic, and unpack the result bits back to floats.
// Memory-bound: 256 MiB total traffic -> ~41 us floor at 6.3 TB/s.

__global__ __launch_bounds__(256) void spike_sqrt_kernel(const float* __restrict__ x,
                                                         float* __restrict__ out,
                                                         int nrows) {
    int row = blockIdx.x * blockDim.x + threadIdx.x;
    if (row >= nrows) return;

    // ---- gather 32 bits (MSB-first in memory) into w -------------------
    const float4* __restrict__ xr = reinterpret_cast<const float4*>(x) + (size_t)row * 8;
    uint32_t w = 0;
#pragma unroll
    for (int i = 0; i < 8; ++i) {
        float4 v = xr[i];
        uint32_t b0 = (v.x != 0.0f);
        uint32_t b1 = (v.y != 0.0f);
        uint32_t b2 = (v.z != 0.0f);
        uint32_t b3 = (v.w != 0.0f);
        w = (w << 4) | (b0 << 3) | (b1 << 2) | (b2 << 1) | b3;
    }

    uint32_t s = w >> 31;
    uint32_t E = (w >> 23) & 0xFFu;
    uint32_t M = w & 0x7FFFFFu;

    bool e_all_one = (E == 0xFFu);
    bool e_is_zero = (E == 0u);
    bool m_is_zero = (M == 0u);
    bool is_zero = e_is_zero && m_is_zero;
    bool is_inf  = e_all_one && m_is_zero;
    bool is_nan  = e_all_one && !m_is_zero;
    bool is_neg  = (s != 0u) && !is_zero;

    // reference's "exp_is_odd" = NOT exponent-LSB = (E even)
    uint32_t e_even = ((E & 1u) == 0u);
    uint32_t addc   = e_even ? 126u : 127u;
    uint32_t Er     = ((E + addc) & 0x1FFu) >> 1;   // 9-bit sum, drop LSB

    uint32_t mant24 = M | 0x800000u;                 // implicit 1 (even for denorms, per ref)
    uint32_t rad25  = e_even ? (mant24 << 1) : mant24;

    // ---- restoring digit-by-digit sqrt: radicand = rad25 << 23, 25 digits
    // padded sequence = (rad25 << 23) << 2 = rad25 << 25 (50 bits, pairs MSB-first)
    uint64_t rad = (uint64_t)rad25 << 25;
    uint32_t rem = 0, q = 0;
#pragma unroll
    for (int i = 24; i >= 0; --i) {
        rem = (rem << 2) | (uint32_t)((rad >> (2 * i)) & 3ull);
        uint32_t t = (q << 2) | 1u;                  // trial divisor 4Q+1
        if (rem >= t) { rem -= t; q = (q << 1) | 1u; }
        else          {           q = (q << 1);      }
    }

    // ---- round to nearest even; carry out of 23 bits is DROPPED (per ref)
    uint32_t round_bit  = q & 1u;
    uint32_t mant23     = (q >> 1) & 0x7FFFFFu;      // drop Q's leading bit
    uint32_t lsb        = mant23 & 1u;
    uint32_t sticky     = (rem != 0u);
    uint32_t round_up   = round_bit & (sticky | lsb);
    uint32_t mant_final = (mant23 + round_up) & 0x7FFFFFu;

    uint32_t res = (Er << 23) | mant_final;          // sign bit 0
    if (is_nan || is_neg) res = 0x7FC00000u;         // qNaN  [0][1]*9[0]*22
    if (is_zero)          res = 0u;
    if (is_inf)           res = 0x7F800000u;         // +inf overrides (even -inf, per ref)

    // ---- scatter 32 result bits back to floats (MSB-first) -------------
    float4* __restrict__ orow = reinterpret_cast<float4*>(out) + (size_t)row * 8;
#pragma unroll
    for (int i = 0; i < 8; ++i) {
        float4 v;
        v.x = (float)((res >> (31 - 4 * i)) & 1u);
        v.y = (float)((res >> (30 - 4 * i)) & 1u);
        v.z = (float)((res >> (29 - 4 * i)) & 1u);
        v.w = (float)((res >> (28 - 4 * i)) & 1u);
        orow[i] = v;
    }
}

extern "C" void kernel_launch(void* const* d_in, const int* in_sizes, int n_in,
                              void* d_out, int out_size, void* d_ws, size_t ws_size,
                              hipStream_t stream) {
    const float* x = (const float*)d_in[0];
    float* out = (float*)d_out;
    int nrows = in_sizes[0] / 32;   // 1048576
    int block = 256;
    int grid = (nrows + block - 1) / block;
    spike_sqrt_kernel<<<grid, block, 0, stream>>>(x, out, nrows);
}

// Round 2
// 43.107 us; speedup vs baseline: 1.5885x; 1.5885x over previous
//
#include <hip/hip_runtime.h>
#include <stdint.h>

// SpikeFP32Sqrt: reference emulates fp32 sqrt via soft logic gates on 0/1 floats.
// R1: fix memory coalescing. R0 had each lane touching its own 128-B row in
// 16-B pieces -> 64 cache lines per vmem instruction -> transaction/latency
// bound (2.1 TB/s, VALUBusy 10%). Now each wave owns 64 rows and loads/stores
// fully coalesced float4 (1 KiB per wave-instruction); rows are assembled
// in-register via an 8-lane __shfl_xor OR-butterfly (no LDS, no redundancy).

__global__ __launch_bounds__(256) void spike_sqrt_kernel(const float* __restrict__ x,
                                                         float* __restrict__ out,
                                                         int nrows) {
    const int lane = threadIdx.x & 63;
    const int waveInBlock = threadIdx.x >> 6;
    const int gw = blockIdx.x * 4 + waveInBlock;       // global wave id
    const size_t baseRow = (size_t)gw * 64;            // 64 rows per wave
    if (baseRow >= (size_t)nrows) return;

    // ---- coalesced load + in-register transpose -------------------------
    // float4 index (row*8 + col): round j, lane l -> row 8j+(l>>3), col l&7.
    const float4* __restrict__ xt = reinterpret_cast<const float4*>(x) + baseRow * 8;
    const int nibShift = 28 - 4 * (lane & 7);          // MSB-first nibble slot
    uint32_t w = 0;
#pragma unroll
    for (int j = 0; j < 8; ++j) {
        float4 v = xt[j * 64 + lane];
        uint32_t nib = ((uint32_t)(v.x != 0.0f) << 3) |
                       ((uint32_t)(v.y != 0.0f) << 2) |
                       ((uint32_t)(v.z != 0.0f) << 1) |
                        (uint32_t)(v.w != 0.0f);
        uint32_t part = nib << nibShift;
        // OR-butterfly across the 8-lane group: all 8 lanes get the full word
        part |= __shfl_xor((int)part, 1);
        part |= __shfl_xor((int)part, 2);
        part |= __shfl_xor((int)part, 4);
        if ((lane & 7) == j) w = part;                 // lane l keeps row 8(l&7)+(l>>3)
    }

    // ---- integer transcription of the gate-level sqrt (verified R0) -----
    uint32_t s = w >> 31;
    uint32_t E = (w >> 23) & 0xFFu;
    uint32_t M = w & 0x7FFFFFu;

    bool e_all_one = (E == 0xFFu);
    bool e_is_zero = (E == 0u);
    bool m_is_zero = (M == 0u);
    bool is_zero = e_is_zero && m_is_zero;
    bool is_inf  = e_all_one && m_is_zero;
    bool is_nan  = e_all_one && !m_is_zero;
    bool is_neg  = (s != 0u) && !is_zero;

    uint32_t e_even = ((E & 1u) == 0u);                // ref's "exp_is_odd"
    uint32_t addc   = e_even ? 126u : 127u;
    uint32_t Er     = ((E + addc) & 0x1FFu) >> 1;

    uint32_t mant24 = M | 0x800000u;
    uint32_t rad25  = e_even ? (mant24 << 1) : mant24;

    uint64_t rad = (uint64_t)rad25 << 25;
    uint32_t rem = 0, q = 0;
#pragma unroll
    for (int i = 24; i >= 0; --i) {
        rem = (rem << 2) | (uint32_t)((rad >> (2 * i)) & 3ull);
        uint32_t t = (q << 2) | 1u;
        if (rem >= t) { rem -= t; q = (q << 1) | 1u; }
        else          {           q = (q << 1);      }
    }

    uint32_t round_bit  = q & 1u;
    uint32_t mant23     = (q >> 1) & 0x7FFFFFu;
    uint32_t lsb        = mant23 & 1u;
    uint32_t sticky     = (rem != 0u);
    uint32_t round_up   = round_bit & (sticky | lsb);
    uint32_t mant_final = (mant23 + round_up) & 0x7FFFFFu;

    uint32_t res = (Er << 23) | mant_final;
    if (is_nan || is_neg) res = 0x7FC00000u;
    if (is_zero)          res = 0u;
    if (is_inf)           res = 0x7F800000u;

    // ---- in-register transpose + coalesced store -------------------------
    // round j, lane l writes row 8j+(l>>3), col l&7; that row's result is
    // held by lane (l&56)|j  (since holder k' has row 8(k'&7)+(k'>>3)).
    float4* __restrict__ ot = reinterpret_cast<float4*>(out) + baseRow * 8;
#pragma unroll
    for (int j = 0; j < 8; ++j) {
        uint32_t r = (uint32_t)__shfl((int)res, (lane & 56) | j);
        uint32_t nib = (r >> nibShift) & 0xFu;
        float4 v;
        v.x = (float)((nib >> 3) & 1u);
        v.y = (float)((nib >> 2) & 1u);
        v.z = (float)((nib >> 1) & 1u);
        v.w = (float)(nib & 1u);
        ot[j * 64 + lane] = v;
    }
}

extern "C" void kernel_launch(void* const* d_in, const int* in_sizes, int n_in,
                              void* d_out, int out_size, void* d_ws, size_t ws_size,
                              hipStream_t stream) {
    const float* x = (const float*)d_in[0];
    float* out = (float*)d_out;
    int nrows = in_sizes[0] / 32;       // 1048576
    int rowsPerBlock = 256;             // 4 waves * 64 rows
    int grid = (nrows + rowsPerBlock - 1) / rowsPerBlock;
    spike_sqrt_kernel<<<grid, 256, 0, stream>>>(x, out, nrows);
}

// Round 4
// 42.779 us; speedup vs baseline: 1.6007x; 1.0077x over previous
//
#include <hip/hip_runtime.h>
#include <stdint.h>

// SpikeFP32Sqrt — R3 (= R2 with compile fix).
// R1 post-mortem: 43 us, ~4.7 TB/s effective (74% of achievable). Remaining:
//  (a) output writes evict the input from L3 (FETCH=65MB of a 131MB input)
//      -> non-temporal stores keep the input L3-resident across replays;
//  (b) 32 cross-lane DS ops/lane with 3-deep dependent chains
//      -> 8x8 nibble-matrix transpose: 3 shfl_xor + bitops (6 DS ops total).
// R2 failed: __builtin_nontemporal_store rejects HIP_vector_type<float,4>;
// use a native clang ext_vector float4 instead.

typedef float vfloat4 __attribute__((ext_vector_type(4)));

__device__ __forceinline__ uint32_t nibrev(uint32_t x) {
    // reverse the 8 nibbles of x (slot k -> slot 7-k)
    x = __builtin_bswap32(x);
    return ((x & 0x0F0F0F0Fu) << 4) | ((x >> 4) & 0x0F0F0F0Fu);
}

__device__ __forceinline__ uint32_t xpose8(uint32_t A, int l7) {
    // 8x8 nibble transpose across an 8-lane group:
    // out[lane c].slot j = in[lane j].slot c     (slots are LSB-first nibbles)
    {
        uint32_t o = (uint32_t)__shfl_xor((int)A, 1);
        A = (l7 & 1) ? ((A & 0xF0F0F0F0u) | ((o >> 4) & 0x0F0F0F0Fu))
                     : ((A & 0x0F0F0F0Fu) | ((o & 0x0F0F0F0Fu) << 4));
    }
    {
        uint32_t o = (uint32_t)__shfl_xor((int)A, 2);
        A = (l7 & 2) ? ((A & 0xFF00FF00u) | ((o >> 8) & 0x00FF00FFu))
                     : ((A & 0x00FF00FFu) | ((o & 0x00FF00FFu) << 8));
    }
    {
        uint32_t o = (uint32_t)__shfl_xor((int)A, 4);
        A = (l7 & 4) ? ((A & 0xFFFF0000u) | (o >> 16))
                     : ((A & 0x0000FFFFu) | (o << 16));
    }
    return A;
}

__global__ __launch_bounds__(256) void spike_sqrt_kernel(const float* __restrict__ x,
                                                         float* __restrict__ out,
                                                         int nrows) {
    const int lane = threadIdx.x & 63;
    const int l7 = lane & 7;
    const int waveInBlock = threadIdx.x >> 6;
    const int gw = blockIdx.x * 4 + waveInBlock;       // global wave id
    const size_t baseRow = (size_t)gw * 64;            // 64 rows per wave
    if (baseRow >= (size_t)nrows) return;

    // ---- coalesced loads; pack round-j nibble into slot j of A ----------
    // float4 index = row*8 + col: round j, lane l -> row 8j+(l>>3), col l&7.
    // A[lane (g,c)].slot j = nibble c (MSB-first col group) of row 8j+g.
    const vfloat4* __restrict__ xt = reinterpret_cast<const vfloat4*>(x) + baseRow * 8;
    uint32_t A = 0;
#pragma unroll
    for (int j = 0; j < 8; ++j) {
        vfloat4 v = xt[j * 64 + lane];
        uint32_t nib = ((uint32_t)(v.x != 0.0f) << 3) |
                       ((uint32_t)(v.y != 0.0f) << 2) |
                       ((uint32_t)(v.z != 0.0f) << 1) |
                        (uint32_t)(v.w != 0.0f);
        A |= nib << (4 * j);
    }
    // transpose: slot j of lane c becomes nibble j(MSB-first) of row 8c+g;
    // nibble-reverse to get the MSB-first 32-bit word of row 8(l&7)+(l>>3).
    uint32_t w = nibrev(xpose8(A, l7));

    // ---- integer transcription of the gate-level sqrt (verified R0) -----
    uint32_t s = w >> 31;
    uint32_t E = (w >> 23) & 0xFFu;
    uint32_t M = w & 0x7FFFFFu;

    bool e_all_one = (E == 0xFFu);
    bool e_is_zero = (E == 0u);
    bool m_is_zero = (M == 0u);
    bool is_zero = e_is_zero && m_is_zero;
    bool is_inf  = e_all_one && m_is_zero;
    bool is_nan  = e_all_one && !m_is_zero;
    bool is_neg  = (s != 0u) && !is_zero;

    uint32_t e_even = ((E & 1u) == 0u);                // ref's "exp_is_odd"
    uint32_t addc   = e_even ? 126u : 127u;
    uint32_t Er     = ((E + addc) & 0x1FFu) >> 1;

    uint32_t mant24 = M | 0x800000u;
    uint32_t rad25  = e_even ? (mant24 << 1) : mant24;

    uint64_t rad = (uint64_t)rad25 << 25;
    uint32_t rem = 0, q = 0;
#pragma unroll
    for (int i = 24; i >= 0; --i) {
        rem = (rem << 2) | (uint32_t)((rad >> (2 * i)) & 3ull);
        uint32_t t = (q << 2) | 1u;
        if (rem >= t) { rem -= t; q = (q << 1) | 1u; }
        else          {           q = (q << 1);      }
    }

    uint32_t round_bit  = q & 1u;
    uint32_t mant23     = (q >> 1) & 0x7FFFFFu;
    uint32_t lsb        = mant23 & 1u;
    uint32_t sticky     = (rem != 0u);
    uint32_t round_up   = round_bit & (sticky | lsb);
    uint32_t mant_final = (mant23 + round_up) & 0x7FFFFFu;

    uint32_t res = (Er << 23) | mant_final;
    if (is_nan || is_neg) res = 0x7FC00000u;
    if (is_zero)          res = 0u;
    if (is_inf)           res = 0x7F800000u;

    // ---- inverse transform + coalesced non-temporal stores --------------
    // V = nibrev(res): slot j' = MSB-nibble j' of my row. Transpose:
    // V^[lane c].slot j = MSB-nibble c of row 8j+g = what round-j store needs.
    uint32_t V = xpose8(nibrev(res), l7);
    vfloat4* __restrict__ ot = reinterpret_cast<vfloat4*>(out) + baseRow * 8;
#pragma unroll
    for (int j = 0; j < 8; ++j) {
        uint32_t nib = (V >> (4 * j)) & 0xFu;
        vfloat4 v;
        v.x = (float)((nib >> 3) & 1u);
        v.y = (float)((nib >> 2) & 1u);
        v.z = (float)((nib >> 1) & 1u);
        v.w = (float)(nib & 1u);
        __builtin_nontemporal_store(v, &ot[j * 64 + lane]);
    }
}

extern "C" void kernel_launch(void* const* d_in, const int* in_sizes, int n_in,
                              void* d_out, int out_size, void* d_ws, size_t ws_size,
                              hipStream_t stream) {
    const float* x = (const float*)d_in[0];
    float* out = (float*)d_out;
    int nrows = in_sizes[0] / 32;       // 1048576
    int rowsPerBlock = 256;             // 4 waves * 64 rows
    int grid = (nrows + rowsPerBlock - 1) / rowsPerBlock;
    spike_sqrt_kernel<<<grid, 256, 0, stream>>>(x, out, nrows);
}